// Round 10
// baseline (93.687 us; speedup 1.0000x reference)
//
#include <hip/hip_runtime.h>
#include <cstdint>

typedef float v2f __attribute__((ext_vector_type(2)));

namespace {
constexpr int kG = 262144;                    // 64^3 cells
constexpr int kB = 2;
constexpr int kN = 8192;
constexpr int kPts = kB * kN;                 // 16384 points
constexpr float kDX = 1.0f / 64.0f;
constexpr float kRad2 = 0.00152587890625f;    // (2.5/64)^2, exact
constexpr float kInvRad = 25.6f;              // 1/RADIUS
constexpr float kEps = 1e-12f;
constexpr float kFourOverPi = 1.27323954473516268615f;

constexpr int PPB = 2;                        // points per block (1 wave each)
constexpr int THREADS = PPB * 64;             // 128
constexpr int MAXREC = 96;                    // nv<=81, padded to x8
constexpr int SLOT = 12;                      // floats/record: 48B stride cycles banks
constexpr int NFLAT = 96;                     // compact flat-index array
constexpr int GSTRIDE = MAXREC * SLOT + NFLAT; // 1248 floats per point region
constexpr int NBUCKET = 8192;                 // (batch bit) << 12 | morton16^3
}

__device__ __forceinline__ float sgnf(float v) {
    return (v > 0.f) ? 1.f : ((v < 0.f) ? -1.f : 0.f);
}

// ---- single-block counting sort of points by (batch, Morton 16^3 coarse cell) ----
__global__ __launch_bounds__(1024) void sort_points_k(const float* __restrict__ pos,
                                                      int* __restrict__ order) {
    __shared__ int hist[NBUCKET];
    __shared__ int aux[1024];
    const int t = threadIdx.x;
    for (int i = t; i < NBUCKET; i += 1024) hist[i] = 0;
    __syncthreads();

    int karr[16];
#pragma unroll
    for (int j = 0; j < 16; ++j) {
        int p = j * 1024 + t;
        float px = pos[p * 3], py = pos[p * 3 + 1], pz = pos[p * 3 + 2];
        int cx = ((int)floorf(px * 64.f)) >> 2;   // 0..15
        int cy = ((int)floorf(py * 64.f)) >> 2;
        int cz = ((int)floorf(pz * 64.f)) >> 2;
        int rx = (cx & 1) | ((cx & 2) << 2) | ((cx & 4) << 4) | ((cx & 8) << 6);
        int ry = (cy & 1) | ((cy & 2) << 2) | ((cy & 4) << 4) | ((cy & 8) << 6);
        int rz = (cz & 1) | ((cz & 2) << 2) | ((cz & 4) << 4) | ((cz & 8) << 6);
        int key = (rx | (ry << 1) | (rz << 2)) | ((p >> 13) << 12);
        karr[j] = key;
        atomicAdd(&hist[key], 1);
    }
    __syncthreads();

    // exclusive scan of 8192 buckets: per-thread sum of 8, block scan, write back
    const int base = t * 8;
    int h[8];
    int s = 0;
#pragma unroll
    for (int k = 0; k < 8; ++k) { h[k] = hist[base + k]; s += h[k]; }
    aux[t] = s;
    __syncthreads();
    for (int off = 1; off < 1024; off <<= 1) {
        int v = (t >= off) ? aux[t - off] : 0;
        __syncthreads();
        aux[t] += v;
        __syncthreads();
    }
    int excl = aux[t] - s;
#pragma unroll
    for (int k = 0; k < 8; ++k) { hist[base + k] = excl; excl += h[k]; }
    __syncthreads();

    // scatter (hist now = running cursors). order content is race-ordered but the
    // main kernel's per-point math is order-independent -> output deterministic.
#pragma unroll
    for (int j = 0; j < 16; ++j) {
        int p = j * 1024 + t;
        int idx = atomicAdd(&hist[karr[j]], 1);
        order[idx] = p;
    }
}

// ---- transpose [B][C][G] -> [B][G][C] so per-cell channel gathers are one 64B line ----
__global__ __launch_bounds__(256) void transpose_feat_k(const float* __restrict__ in,
                                                        float* __restrict__ feat) {
    int idx = blockIdx.x * 256 + threadIdx.x;      // over B*G
    if (idx >= kB * kG) return;
    int b = idx >> 18;
    int g = idx & (kG - 1);
    float v[16];
#pragma unroll
    for (int c = 0; c < 16; ++c) v[c] = in[((size_t)(b * 16 + c)) * kG + g];
    float4* dst = reinterpret_cast<float4*>(feat + (size_t)idx * 16);
    dst[0] = make_float4(v[0], v[1], v[2], v[3]);
    dst[1] = make_float4(v[4], v[5], v[6], v[7]);
    dst[2] = make_float4(v[8], v[9], v[10], v[11]);
    dst[3] = make_float4(v[12], v[13], v[14], v[15]);
}

__global__ __launch_bounds__(THREADS) void cconv_main(
    const float* __restrict__ input, const float* __restrict__ pos,
    const float* __restrict__ W, const float* __restrict__ feat,
    const int* __restrict__ order, float* __restrict__ out,
    int use_feat, int use_sort)
{
    // each wave (point) touches only its own LDS region; same-wave DS ops are
    // ordered -> no __syncthreads, waves fully decoupled.
    __shared__ __align__(16) float rec[PPB * GSTRIDE];   // 9,984 B

    const int tid = threadIdx.x;
    const int wv = tid >> 6;            // point-in-block (one wave per point)
    const int lane = tid & 63;
    const int sg = lane >> 4;           // sub-group 0..3
    const int lig = lane & 15;          // channel lane within sub-group
    // XCD-contiguous swizzle: 8192 blocks = 8 XCDs x 1024 -> each XCD gets a
    // contiguous sorted range (locality only matters when sorted; harmless else).
    const int bid = (int)blockIdx.x;
    const int swz = use_sort ? ((bid & 7) * 1024 + (bid >> 3)) : bid;
    const int gid = swz * PPB + wv;
    const int pt = use_sort ? order[gid] : gid;
    const int b = pt >> 13;             // / kN (original batch of this point)

    const float px = pos[pt * 3 + 0];
    const float py = pos[pt * 3 + 1];
    const float pz = pos[pt * 3 + 2];
    const int bx = (int)floorf(px * 64.f);
    const int by = (int)floorf(py * 64.f);
    const int bz = (int)floorf(pz * 64.f);

    float* grec = rec + wv * GSTRIDE;
    int* iflats = reinterpret_cast<int*>(grec + MAXREC * SLOT);
    int nv = 0;

    // ---- pass 1a: validity over 216 candidates, full-wave ballot-compact ----
#pragma unroll
    for (int it = 0; it < 4; ++it) {
        int k = it * 64 + lane;
        bool valid = false;
        float rx = 0.f, ry = 0.f, rz = 0.f;
        int flat16 = 0;
        if (k < 216) {
            int a = k / 36;
            int r = k - a * 36;
            int b1 = r / 6;
            int c1 = r - b1 * 6;
            int g0 = bx + a - 2, g1 = by + b1 - 2, g2 = bz + c1 - 2;
            bool inb = (g0 >= 0) & (g0 < 64) & (g1 >= 0) & (g1 < 64) &
                       (g2 >= 0) & (g2 < 64);
            int q0 = min(max(g0, 0), 63);
            int q1 = min(max(g1, 0), 63);
            int q2 = min(max(g2, 0), 63);
            flat16 = ((q0 * 64 + q1) * 64 + q2) << 4;   // pre-scaled by C=16
            // grid_pos[i] == i*DX exactly -> compute, don't load
            rx = __fsub_rn((float)q0 * kDX, px);
            ry = __fsub_rn((float)q1 * kDX, py);
            rz = __fsub_rn((float)q2 * kDX, pz);
            // forbid fma-contraction so the <= compare matches XLA mul-then-add
            float d2 = __fadd_rn(__fadd_rn(__fmul_rn(rx, rx), __fmul_rn(ry, ry)),
                                 __fmul_rn(rz, rz));
            valid = inb && (d2 <= kRad2);
        }
        unsigned long long ball = __ballot(valid);
        if (valid) {
            int slot = nv + __popcll(ball & ((1ull << lane) - 1ull));
            *reinterpret_cast<float4*>(grec + slot * SLOT) =
                make_float4(rx, ry, rz, 0.f);
            iflats[slot] = flat16;
        }
        nv += (int)__popcll(ball);
    }
    __builtin_amdgcn_wave_barrier();

    // ---- zero-pad records + flats up to 96 (branch-free padded pass 2) ----
    for (int z = nv + lane; z < MAXREC; z += 64) {
        float4 zf = make_float4(0.f, 0.f, 0.f, 0.f);
        float4* zp = reinterpret_cast<float4*>(grec + z * SLOT);
        zp[0] = zf; zp[1] = zf; zp[2] = zf;    // all xy-products zero -> no contribution
        iflats[z] = 0;
    }
    __builtin_amdgcn_wave_barrier();

    // ---- prime the 2-bank (32-record-deep) feature gather pipeline ----
    const float* fbp = use_feat ? (feat + (size_t)b * kG * 16)
                                : (input + (size_t)b * 16 * kG);
#define LDF(IDX) (use_feat ? fbp[(size_t)iflats[(IDX)] + lig]                 \
                           : fbp[(size_t)lig * kG + (iflats[(IDX)] >> 4)])
    float fa0 = LDF(sg),      fa1 = LDF(sg + 4);
    float fa2 = LDF(sg + 8),  fa3 = LDF(sg + 12);
    float fb0 = LDF(sg + 16), fb1 = LDF(sg + 20);
    float fb2 = LDF(sg + 24), fb3 = LDF(sg + 28);

    // ---- pass 1b: mapping + hat weights -> 9 xy-products + wz0,wz1 ----
    for (int s = lane; s < nv; s += 64) {
        float* rp = grec + s * SLOT;
        float4 rc = *reinterpret_cast<const float4*>(rp);
        float ux = rc.x * kInvRad, uy = rc.y * kInvRad, uz = rc.z * kInvRad;

        // sphere -> cylinder (branch-free, HW rcp/rsq/sqrt: ~1ulp)
        float xx = ux * ux, yy = uy * uy, zz = uz * uz;
        float xy2 = xx + yy;
        float sq = xy2 + zz;
        float nrm = __builtin_amdgcn_sqrtf(fmaxf(sq, kEps));
        bool cap = (1.25f * zz > xy2);
        float scap = __builtin_amdgcn_sqrtf(3.f * nrm) *
                     __builtin_amdgcn_rsqf(nrm + fabsf(uz) + kEps);
        float sside = nrm * __builtin_amdgcn_rsqf(fmaxf(xy2, kEps));
        float sc = cap ? scap : sside;
        float xc = ux * sc, yc = uy * sc;
        float zc = cap ? sgnf(uz) * nrm : 1.5f * uz;
        if (sq <= kEps) { xc = 0.f; yc = 0.f; zc = 0.f; }

        // cylinder -> cube (single atan poly path)
        float xy2b = xc * xc + yc * yc;
        float nxy = __builtin_amdgcn_sqrtf(fmaxf(xy2b, kEps));
        bool xdom = (fabsf(yc) <= fabsf(xc));
        float num = xdom ? yc : xc;
        float den = xdom ? xc : yc;
        float dsafe = (fabsf(den) > kEps) ? den : 1.0f;
        float r = num * __builtin_amdgcn_rcpf(dsafe);     // |r| <= 1
        float r2 = r * r;
        float at = -0.01172120f;
        at = at * r2 + 0.05265332f;
        at = at * r2 - 0.11643287f;
        at = at * r2 + 0.19354346f;
        at = at * r2 - 0.33262347f;
        at = at * r2 + 0.99997726f;
        at = at * r;                                      // ~atan(r), err ~1e-5
        float tt = sgnf(den) * nxy;
        float g = tt * kFourOverPi * at;
        float xo = xdom ? tt : g;
        float yo = xdom ? g : tt;
        if (xy2b <= kEps) { xo = 0.f; yo = 0.f; }
        float zo = zc;

        // hat weights: c = clamp(v+1, 0, 2) (== ref's (v*0.5+0.5)*2 exactly)
        float tx = fminf(fmaxf(xo + 1.f, 0.f), 2.f) - 1.f;
        float ty = fminf(fmaxf(yo + 1.f, 0.f), 2.f) - 1.f;
        float tz = fminf(fmaxf(zo + 1.f, 0.f), 2.f) - 1.f;
        float wx0 = fmaxf(0.f, -tx), wx1 = 1.f - fabsf(tx), wx2 = fmaxf(0.f, tx);
        float wy0 = fmaxf(0.f, -ty), wy1 = 1.f - fabsf(ty), wy2 = fmaxf(0.f, ty);
        float wz0 = fmaxf(0.f, -tz), wz1 = 1.f - fabsf(tz);
        // wz2 reconstructed in pass 2 as (1-wz0)-wz1

        float4* rp4 = reinterpret_cast<float4*>(rp);
        rp4[0] = make_float4(wx0 * wy0, wx0 * wy1, wx0 * wy2, wx1 * wy0);
        rp4[1] = make_float4(wx1 * wy1, wx1 * wy2, wx2 * wy0, wx2 * wy1);
        rp4[2] = make_float4(wx2 * wy2, wz0, wz1, 0.f);
    }
    __builtin_amdgcn_wave_barrier();

    // ---- pass 2: unrolled bodies (16 rec) + half-body tail (8 rec), pk FMAs ----
    v2f az0_01 = {0.f, 0.f}, az1_01 = {0.f, 0.f}, az2_01 = {0.f, 0.f};
    v2f az0_23 = {0.f, 0.f}, az1_23 = {0.f, 0.f}, az2_23 = {0.f, 0.f};
    v2f az0_45 = {0.f, 0.f}, az1_45 = {0.f, 0.f}, az2_45 = {0.f, 0.f};
    v2f az0_67 = {0.f, 0.f}, az1_67 = {0.f, 0.f}, az2_67 = {0.f, 0.f};
    float a8_0 = 0.f, a8_1 = 0.f, a8_2 = 0.f;

    const int R = (nv + 7) & ~7;        // pad to x8, <= 88
    const int F = R >> 4;               // number of full 16-record bodies
    const bool HB = (R & 8) != 0;       // trailing 8-record half body

#define REC_FMA(S, FV)                                                        \
  {                                                                           \
    const float4* rp4_ = reinterpret_cast<const float4*>(grec + (S) * SLOT);  \
    float4 Wa = rp4_[0], Wb = rp4_[1], Wc = rp4_[2];                          \
    float m0 = Wc.y * (FV), m1 = Wc.z * (FV);                                 \
    float m2 = ((1.f - Wc.y) - Wc.z) * (FV);                                  \
    v2f mz0 = {m0, m0}, mz1 = {m1, m1}, mz2 = {m2, m2};                       \
    v2f p01 = {Wa.x, Wa.y}, p23 = {Wa.z, Wa.w};                               \
    v2f p45 = {Wb.x, Wb.y}, p67 = {Wb.z, Wb.w};                               \
    az0_01 = __builtin_elementwise_fma(p01, mz0, az0_01);                     \
    az1_01 = __builtin_elementwise_fma(p01, mz1, az1_01);                     \
    az2_01 = __builtin_elementwise_fma(p01, mz2, az2_01);                     \
    az0_23 = __builtin_elementwise_fma(p23, mz0, az0_23);                     \
    az1_23 = __builtin_elementwise_fma(p23, mz1, az1_23);                     \
    az2_23 = __builtin_elementwise_fma(p23, mz2, az2_23);                     \
    az0_45 = __builtin_elementwise_fma(p45, mz0, az0_45);                     \
    az1_45 = __builtin_elementwise_fma(p45, mz1, az1_45);                     \
    az2_45 = __builtin_elementwise_fma(p45, mz2, az2_45);                     \
    az0_67 = __builtin_elementwise_fma(p67, mz0, az0_67);                     \
    az1_67 = __builtin_elementwise_fma(p67, mz1, az1_67);                     \
    az2_67 = __builtin_elementwise_fma(p67, mz2, az2_67);                     \
    a8_0 = __builtin_fmaf(Wc.x, m0, a8_0);                                    \
    a8_1 = __builtin_fmaf(Wc.x, m1, a8_1);                                    \
    a8_2 = __builtin_fmaf(Wc.x, m2, a8_2);                                    \
  }

    // body KK executes iff KK < F (full) or KK == F && HB (half: first 8 only).
    // feature loads for body KK+2 issued at body KK (2-bank rotation, 32 deep).
#define P2BODY(KK, F0_, F1_, F2_, F3_)                                        \
  {                                                                           \
    const int rb_ = (KK) * 16 + sg;                                           \
    const bool nxt_ = ((KK) + 2 < F) || ((KK) + 2 == F && HB);                \
    float n0_ = 0.f, n1_ = 0.f, n2_ = 0.f, n3_ = 0.f;                         \
    if (nxt_) {                                                               \
      n0_ = LDF(rb_ + 32); n1_ = LDF(rb_ + 36);                               \
      n2_ = LDF(rb_ + 40); n3_ = LDF(rb_ + 44);                               \
    }                                                                         \
    REC_FMA(rb_, F0_); REC_FMA(rb_ + 4, F1_);                                 \
    if ((KK) < F) { REC_FMA(rb_ + 8, F2_); REC_FMA(rb_ + 12, F3_); }          \
    if (nxt_) { F0_ = n0_; F1_ = n1_; F2_ = n2_; F3_ = n3_; }                 \
  }

    /* body 0 always exists (nv >= 1) */ P2BODY(0, fa0, fa1, fa2, fa3)
    if (1 < F || (1 == F && HB)) P2BODY(1, fb0, fb1, fb2, fb3)
    if (2 < F || (2 == F && HB)) P2BODY(2, fa0, fa1, fa2, fa3)
    if (3 < F || (3 == F && HB)) P2BODY(3, fb0, fb1, fb2, fb3)
    if (4 < F || (4 == F && HB)) P2BODY(4, fa0, fa1, fa2, fa3)
    if (5 == F && HB)            P2BODY(5, fb0, fb1, fb2, fb3)

    // ---- scatter acc into t = 3i+z order (register renames, zero cost) ----
    float acc[28] = {
        az0_01.x, az1_01.x, az2_01.x,   // i=0
        az0_01.y, az1_01.y, az2_01.y,   // i=1
        az0_23.x, az1_23.x, az2_23.x,   // i=2
        az0_23.y, az1_23.y, az2_23.y,   // i=3
        az0_45.x, az1_45.x, az2_45.x,   // i=4
        az0_45.y, az1_45.y, az2_45.y,   // i=5
        az0_67.x, az1_67.x, az2_67.x,   // i=6
        az0_67.y, az1_67.y, az2_67.y,   // i=7
        a8_0,     a8_1,     a8_2,       // i=8
        0.f                              // pad tap 27
    };

    // ---- fold-reduce acc over sub-groups (R4-proven shfl code) ----
    const bool hi32 = (lane >= 32);
    float kp[14];
#pragma unroll
    for (int j = 0; j < 14; ++j) {
        float send = hi32 ? acc[j] : acc[14 + j];
        float recv = __shfl_xor(send, 32);
        kp[j] = (hi32 ? acc[14 + j] : acc[j]) + recv;
    }
    const bool hi16 = (lane & 16) != 0;
    float kk[7];
#pragma unroll
    for (int j = 0; j < 7; ++j) {
        float send = hi16 ? kp[j] : kp[7 + j];
        float recv = __shfl_xor(send, 16);
        kk[j] = (hi16 ? kp[7 + j] : kp[j]) + recv;
    }

    // ---- pass 3: taps t = 7sg+j; partial[d] += kk[j] * W[t][lig][d] ----
    float partial[16];
#pragma unroll
    for (int d = 0; d < 16; ++d) partial[d] = 0.f;
    const float* wbase = W + (sg * 7) * 256 + lig * 16;
#pragma unroll
    for (int j = 0; j < 7; ++j) {
        if (sg * 7 + j < 27) {          // sg3,j6 is the pad tap
            const float4* wr = reinterpret_cast<const float4*>(wbase + j * 256);
            float4 a0 = wr[0], a1 = wr[1], a2 = wr[2], a3 = wr[3];
            float at_ = kk[j];
            partial[0]  += at_ * a0.x; partial[1]  += at_ * a0.y;
            partial[2]  += at_ * a0.z; partial[3]  += at_ * a0.w;
            partial[4]  += at_ * a1.x; partial[5]  += at_ * a1.y;
            partial[6]  += at_ * a1.z; partial[7]  += at_ * a1.w;
            partial[8]  += at_ * a2.x; partial[9]  += at_ * a2.y;
            partial[10] += at_ * a2.z; partial[11] += at_ * a2.w;
            partial[12] += at_ * a3.x; partial[13] += at_ * a3.y;
            partial[14] += at_ * a3.z; partial[15] += at_ * a3.w;
        }
    }

    // ---- fold-reduce 16 partials across the 16-lane group (R4-proven) ----
#pragma unroll
    for (int half = 8; half >= 1; half >>= 1) {
        bool up = (lig & half) != 0;
#pragma unroll
        for (int j = 0; j < half; ++j) {
            float send = up ? partial[j] : partial[j + half];
            float recv = __shfl_xor(send, half);
            partial[j] = (up ? partial[j + half] : partial[j]) + recv;
        }
    }
    float res = partial[0];
    res += __shfl_xor(res, 16);
    res += __shfl_xor(res, 32);
    res = res / fmaxf((float)nv, 1.f);
    if (lane < 16) out[(size_t)pt * 16 + lig] = res;
#undef LDF
#undef REC_FMA
#undef P2BODY
}

extern "C" void kernel_launch(void* const* d_in, const int* in_sizes, int n_in,
                              void* d_out, int out_size, void* d_ws, size_t ws_size,
                              hipStream_t stream) {
    const float* input = (const float*)d_in[0];   // [2,16,64,64,64]
    const float* pos   = (const float*)d_in[1];   // [2,8192,3]
    const float* W     = (const float*)d_in[2];   // [3,3,3,16,16]
    // d_in[3] grid_pos unused: grid_pos[i] == i*DX exactly
    float* out  = (float*)d_out;
    float* feat = (float*)d_ws;

    const size_t feat_bytes = (size_t)kB * kG * 16 * sizeof(float);
    const size_t sort_bytes = (size_t)kPts * sizeof(int);
    int use_feat = (d_ws != nullptr && ws_size >= feat_bytes) ? 1 : 0;
    int use_sort = (d_ws != nullptr && ws_size >= feat_bytes + sort_bytes) ? 1 : 0;
    int* order = (int*)((char*)d_ws + feat_bytes);

    if (use_sort) {
        sort_points_k<<<1, 1024, 0, stream>>>(pos, order);
    }
    if (use_feat) {
        transpose_feat_k<<<(kB * kG + 255) / 256, 256, 0, stream>>>(input, feat);
    }
    cconv_main<<<kPts / PPB, THREADS, 0, stream>>>(input, pos, W, feat, order, out,
                                                   use_feat, use_sort);
}

// Round 11
// 73.756 us; speedup vs baseline: 1.2702x; 1.2702x over previous
//
#include <hip/hip_runtime.h>
#include <cstdint>

typedef float v2f __attribute__((ext_vector_type(2)));

namespace {
constexpr int kG = 262144;                    // 64^3 cells
constexpr int kB = 2;
constexpr int kN = 8192;
constexpr int kPts = kB * kN;                 // 16384 points
constexpr float kDX = 1.0f / 64.0f;
constexpr float kRad2 = 0.00152587890625f;    // (2.5/64)^2, exact
constexpr float kInvRad = 25.6f;              // 1/RADIUS
constexpr float kEps = 1e-12f;
constexpr float kFourOverPi = 1.27323954473516268615f;

constexpr int PPB = 4;                        // points per block (1 wave each)
constexpr int THREADS = PPB * 64;             // 256
constexpr int MAXREC = 96;                    // nv<=81, padded to x8
constexpr int SLOT = 12;                      // floats/record: 48B stride cycles banks
constexpr int NFLAT = 96;                     // compact flat-index array
constexpr int GSTRIDE = MAXREC * SLOT + NFLAT; // 1248 floats per point region
}

// 160 stencil candidates that can ever satisfy dist<=2.5dx: cells with >=2 axes
// at offset in {-2,+3} have min dist^2 >= 8dx^2 > 6.25dx^2 -> never valid.
// Lexicographic (a,b,c) order == reference k-order restricted to the possible set,
// so accumulation order (and absmax) is identical to the full 216 scan.
struct Stencil {
    int v[192];
    constexpr Stencil() : v() {
        int n = 0;
        for (int a = 0; a < 6; ++a)
            for (int b = 0; b < 6; ++b)
                for (int c = 0; c < 6; ++c) {
                    int e = ((a == 0) | (a == 5)) + ((b == 0) | (b == 5)) +
                            ((c == 0) | (c == 5));
                    if (e < 2) { v[n] = a | (b << 8) | (c << 16); ++n; }
                }
        for (; n < 192; ++n) v[n] = 0x7F7F7F;   // sentinel -> out of bounds -> invalid
    }
};
__device__ constexpr Stencil kStencil{};

__device__ __forceinline__ float sgnf(float v) {
    return (v > 0.f) ? 1.f : ((v < 0.f) ? -1.f : 0.f);
}

// ---- transpose [B][C][G] -> [B][G][C] so per-cell channel gathers are one 64B line ----
__global__ __launch_bounds__(256) void transpose_feat_k(const float* __restrict__ in,
                                                        float* __restrict__ feat) {
    int idx = blockIdx.x * 256 + threadIdx.x;      // over B*G
    if (idx >= kB * kG) return;
    int b = idx >> 18;
    int g = idx & (kG - 1);
    float v[16];
#pragma unroll
    for (int c = 0; c < 16; ++c) v[c] = in[((size_t)(b * 16 + c)) * kG + g];
    float4* dst = reinterpret_cast<float4*>(feat + (size_t)idx * 16);
    dst[0] = make_float4(v[0], v[1], v[2], v[3]);
    dst[1] = make_float4(v[4], v[5], v[6], v[7]);
    dst[2] = make_float4(v[8], v[9], v[10], v[11]);
    dst[3] = make_float4(v[12], v[13], v[14], v[15]);
}

template <int USE_FEAT>
__global__ __launch_bounds__(THREADS) void cconv_main(
    const float* __restrict__ input, const float* __restrict__ pos,
    const float* __restrict__ W, const float* __restrict__ feat,
    float* __restrict__ out)
{
    // each wave (point) touches only its own LDS region; same-wave DS ops are
    // ordered -> no __syncthreads, waves fully decoupled.
    __shared__ __align__(16) float rec[PPB * GSTRIDE];

    const int tid = threadIdx.x;
    const int wv = tid >> 6;            // point-in-block (one wave per point)
    const int lane = tid & 63;
    const int sg = lane >> 4;           // sub-group 0..3
    const int lig = lane & 15;          // channel lane within sub-group
    const int pt = blockIdx.x * PPB + wv;
    const int b = pt >> 13;             // / kN

    const float px = pos[pt * 3 + 0];
    const float py = pos[pt * 3 + 1];
    const float pz = pos[pt * 3 + 2];
    const int bx = (int)floorf(px * 64.f);
    const int by = (int)floorf(py * 64.f);
    const int bz = (int)floorf(pz * 64.f);

    float* grec = rec + wv * GSTRIDE;
    int* iflats = reinterpret_cast<int*>(grec + MAXREC * SLOT);
    int nv = 0;

    // ---- pass 1a: validity over 160 possible candidates (LUT), ballot-compact ----
#pragma unroll
    for (int it = 0; it < 3; ++it) {
        int k = it * 64 + lane;
        int pk = kStencil.v[k];
        int a = pk & 0xFF, b1 = (pk >> 8) & 0xFF, c1 = pk >> 16;
        int g0 = bx + a - 2, g1 = by + b1 - 2, g2 = bz + c1 - 2;
        bool inb = (g0 >= 0) & (g0 < 64) & (g1 >= 0) & (g1 < 64) &
                   (g2 >= 0) & (g2 < 64);
        int q0 = min(max(g0, 0), 63);
        int q1 = min(max(g1, 0), 63);
        int q2 = min(max(g2, 0), 63);
        int flat16 = ((q0 * 64 + q1) * 64 + q2) << 4;   // pre-scaled by C=16
        // grid_pos[i] == i*DX exactly -> compute, don't load
        float rx = __fsub_rn((float)q0 * kDX, px);
        float ry = __fsub_rn((float)q1 * kDX, py);
        float rz = __fsub_rn((float)q2 * kDX, pz);
        // forbid fma-contraction so the <= compare matches XLA mul-then-add
        float d2 = __fadd_rn(__fadd_rn(__fmul_rn(rx, rx), __fmul_rn(ry, ry)),
                             __fmul_rn(rz, rz));
        bool valid = inb && (d2 <= kRad2);
        unsigned long long ball = __ballot(valid);
        if (valid) {
            int slot = nv + __popcll(ball & ((1ull << lane) - 1ull));
            *reinterpret_cast<float4*>(grec + slot * SLOT) =
                make_float4(rx, ry, rz, 0.f);
            iflats[slot] = flat16;
        }
        nv += (int)__popcll(ball);
    }
    __builtin_amdgcn_wave_barrier();

    // ---- zero-pad records + flats up to 96 (branch-free padded pass 2) ----
    for (int z = nv + lane; z < MAXREC; z += 64) {
        float4 zf = make_float4(0.f, 0.f, 0.f, 0.f);
        float4* zp = reinterpret_cast<float4*>(grec + z * SLOT);
        zp[0] = zf; zp[1] = zf; zp[2] = zf;    // all xy-products zero -> no contribution
        iflats[z] = 0;
    }
    __builtin_amdgcn_wave_barrier();

    // ---- prime the 2-bank (32-record-deep) feature gather pipeline ----
    const float* fbp = USE_FEAT ? (feat + (size_t)b * kG * 16)
                                : (input + (size_t)b * 16 * kG);
#define LDF(IDX) (USE_FEAT ? fbp[(size_t)iflats[(IDX)] + lig]                 \
                           : fbp[(size_t)lig * kG + (iflats[(IDX)] >> 4)])
    float fa0 = LDF(sg),      fa1 = LDF(sg + 4);
    float fa2 = LDF(sg + 8),  fa3 = LDF(sg + 12);
    float fb0 = LDF(sg + 16), fb1 = LDF(sg + 20);
    float fb2 = LDF(sg + 24), fb3 = LDF(sg + 28);

    // ---- pass 1b: mapping + hat weights -> 9 xy-products + wz0,wz1 ----
    for (int s = lane; s < nv; s += 64) {
        float* rp = grec + s * SLOT;
        float4 rc = *reinterpret_cast<const float4*>(rp);
        float ux = rc.x * kInvRad, uy = rc.y * kInvRad, uz = rc.z * kInvRad;

        // sphere -> cylinder (branch-free, HW rcp/rsq/sqrt: ~1ulp)
        float xx = ux * ux, yy = uy * uy, zz = uz * uz;
        float xy2 = xx + yy;
        float sq = xy2 + zz;
        float nrm = __builtin_amdgcn_sqrtf(fmaxf(sq, kEps));
        bool cap = (1.25f * zz > xy2);
        float scap = __builtin_amdgcn_sqrtf(3.f * nrm) *
                     __builtin_amdgcn_rsqf(nrm + fabsf(uz) + kEps);
        float sside = nrm * __builtin_amdgcn_rsqf(fmaxf(xy2, kEps));
        float sc = cap ? scap : sside;
        float xc = ux * sc, yc = uy * sc;
        float zc = cap ? sgnf(uz) * nrm : 1.5f * uz;
        if (sq <= kEps) { xc = 0.f; yc = 0.f; zc = 0.f; }

        // cylinder -> cube (single atan poly path)
        float xy2b = xc * xc + yc * yc;
        float nxy = __builtin_amdgcn_sqrtf(fmaxf(xy2b, kEps));
        bool xdom = (fabsf(yc) <= fabsf(xc));
        float num = xdom ? yc : xc;
        float den = xdom ? xc : yc;
        float dsafe = (fabsf(den) > kEps) ? den : 1.0f;
        float r = num * __builtin_amdgcn_rcpf(dsafe);     // |r| <= 1
        float r2 = r * r;
        float at = -0.01172120f;
        at = at * r2 + 0.05265332f;
        at = at * r2 - 0.11643287f;
        at = at * r2 + 0.19354346f;
        at = at * r2 - 0.33262347f;
        at = at * r2 + 0.99997726f;
        at = at * r;                                      // ~atan(r), err ~1e-5
        float tt = sgnf(den) * nxy;
        float g = tt * kFourOverPi * at;
        float xo = xdom ? tt : g;
        float yo = xdom ? g : tt;
        if (xy2b <= kEps) { xo = 0.f; yo = 0.f; }
        float zo = zc;

        // hat weights: c = clamp(v+1, 0, 2) (== ref's (v*0.5+0.5)*2 exactly)
        float tx = fminf(fmaxf(xo + 1.f, 0.f), 2.f) - 1.f;
        float ty = fminf(fmaxf(yo + 1.f, 0.f), 2.f) - 1.f;
        float tz = fminf(fmaxf(zo + 1.f, 0.f), 2.f) - 1.f;
        float wx0 = fmaxf(0.f, -tx), wx1 = 1.f - fabsf(tx), wx2 = fmaxf(0.f, tx);
        float wy0 = fmaxf(0.f, -ty), wy1 = 1.f - fabsf(ty), wy2 = fmaxf(0.f, ty);
        float wz0 = fmaxf(0.f, -tz), wz1 = 1.f - fabsf(tz);
        // wz2 reconstructed in pass 2 as (1-wz0)-wz1

        float4* rp4 = reinterpret_cast<float4*>(rp);
        rp4[0] = make_float4(wx0 * wy0, wx0 * wy1, wx0 * wy2, wx1 * wy0);
        rp4[1] = make_float4(wx1 * wy1, wx1 * wy2, wx2 * wy0, wx2 * wy1);
        rp4[2] = make_float4(wx2 * wy2, wz0, wz1, 0.f);
    }
    __builtin_amdgcn_wave_barrier();

    // ---- pass 2: unrolled bodies (16 rec) + half-body tail (8 rec), pk FMAs ----
    v2f az0_01 = {0.f, 0.f}, az1_01 = {0.f, 0.f}, az2_01 = {0.f, 0.f};
    v2f az0_23 = {0.f, 0.f}, az1_23 = {0.f, 0.f}, az2_23 = {0.f, 0.f};
    v2f az0_45 = {0.f, 0.f}, az1_45 = {0.f, 0.f}, az2_45 = {0.f, 0.f};
    v2f az0_67 = {0.f, 0.f}, az1_67 = {0.f, 0.f}, az2_67 = {0.f, 0.f};
    float a8_0 = 0.f, a8_1 = 0.f, a8_2 = 0.f;

    const int R = (nv + 7) & ~7;        // pad to x8, <= 88
    const int F = R >> 4;               // number of full 16-record bodies
    const bool HB = (R & 8) != 0;       // trailing 8-record half body

#define REC_FMA(S, FV)                                                        \
  {                                                                           \
    const float4* rp4_ = reinterpret_cast<const float4*>(grec + (S) * SLOT);  \
    float4 Wa = rp4_[0], Wb = rp4_[1], Wc = rp4_[2];                          \
    float m0 = Wc.y * (FV), m1 = Wc.z * (FV);                                 \
    float m2 = ((1.f - Wc.y) - Wc.z) * (FV);                                  \
    v2f mz0 = {m0, m0}, mz1 = {m1, m1}, mz2 = {m2, m2};                       \
    v2f p01 = {Wa.x, Wa.y}, p23 = {Wa.z, Wa.w};                               \
    v2f p45 = {Wb.x, Wb.y}, p67 = {Wb.z, Wb.w};                               \
    az0_01 = __builtin_elementwise_fma(p01, mz0, az0_01);                     \
    az1_01 = __builtin_elementwise_fma(p01, mz1, az1_01);                     \
    az2_01 = __builtin_elementwise_fma(p01, mz2, az2_01);                     \
    az0_23 = __builtin_elementwise_fma(p23, mz0, az0_23);                     \
    az1_23 = __builtin_elementwise_fma(p23, mz1, az1_23);                     \
    az2_23 = __builtin_elementwise_fma(p23, mz2, az2_23);                     \
    az0_45 = __builtin_elementwise_fma(p45, mz0, az0_45);                     \
    az1_45 = __builtin_elementwise_fma(p45, mz1, az1_45);                     \
    az2_45 = __builtin_elementwise_fma(p45, mz2, az2_45);                     \
    az0_67 = __builtin_elementwise_fma(p67, mz0, az0_67);                     \
    az1_67 = __builtin_elementwise_fma(p67, mz1, az1_67);                     \
    az2_67 = __builtin_elementwise_fma(p67, mz2, az2_67);                     \
    a8_0 = __builtin_fmaf(Wc.x, m0, a8_0);                                    \
    a8_1 = __builtin_fmaf(Wc.x, m1, a8_1);                                    \
    a8_2 = __builtin_fmaf(Wc.x, m2, a8_2);                                    \
  }

    // body KK executes iff KK < F (full) or KK == F && HB (half: first 8 only).
    // feature loads for body KK+2 issued at body KK (2-bank rotation, 32 deep).
#define P2BODY(KK, F0_, F1_, F2_, F3_)                                        \
  {                                                                           \
    const int rb_ = (KK) * 16 + sg;                                           \
    const bool nxt_ = ((KK) + 2 < F) || ((KK) + 2 == F && HB);                \
    float n0_ = 0.f, n1_ = 0.f, n2_ = 0.f, n3_ = 0.f;                         \
    if (nxt_) {                                                               \
      n0_ = LDF(rb_ + 32); n1_ = LDF(rb_ + 36);                               \
      n2_ = LDF(rb_ + 40); n3_ = LDF(rb_ + 44);                               \
    }                                                                         \
    REC_FMA(rb_, F0_); REC_FMA(rb_ + 4, F1_);                                 \
    if ((KK) < F) { REC_FMA(rb_ + 8, F2_); REC_FMA(rb_ + 12, F3_); }          \
    if (nxt_) { F0_ = n0_; F1_ = n1_; F2_ = n2_; F3_ = n3_; }                 \
  }

    /* body 0 always exists (nv >= 1) */ P2BODY(0, fa0, fa1, fa2, fa3)
    if (1 < F || (1 == F && HB)) P2BODY(1, fb0, fb1, fb2, fb3)
    if (2 < F || (2 == F && HB)) P2BODY(2, fa0, fa1, fa2, fa3)
    if (3 < F || (3 == F && HB)) P2BODY(3, fb0, fb1, fb2, fb3)
    if (4 < F || (4 == F && HB)) P2BODY(4, fa0, fa1, fa2, fa3)
    if (5 == F && HB)            P2BODY(5, fb0, fb1, fb2, fb3)

    // ---- scatter acc into t = 3i+z order (register renames, zero cost) ----
    float acc[28] = {
        az0_01.x, az1_01.x, az2_01.x,   // i=0
        az0_01.y, az1_01.y, az2_01.y,   // i=1
        az0_23.x, az1_23.x, az2_23.x,   // i=2
        az0_23.y, az1_23.y, az2_23.y,   // i=3
        az0_45.x, az1_45.x, az2_45.x,   // i=4
        az0_45.y, az1_45.y, az2_45.y,   // i=5
        az0_67.x, az1_67.x, az2_67.x,   // i=6
        az0_67.y, az1_67.y, az2_67.y,   // i=7
        a8_0,     a8_1,     a8_2,       // i=8
        0.f                              // pad tap 27
    };

    // ---- fold-reduce acc over sub-groups (R4-proven shfl code) ----
    const bool hi32 = (lane >= 32);
    float kp[14];
#pragma unroll
    for (int j = 0; j < 14; ++j) {
        float send = hi32 ? acc[j] : acc[14 + j];
        float recv = __shfl_xor(send, 32);
        kp[j] = (hi32 ? acc[14 + j] : acc[j]) + recv;
    }
    const bool hi16 = (lane & 16) != 0;
    float kk[7];
#pragma unroll
    for (int j = 0; j < 7; ++j) {
        float send = hi16 ? kp[j] : kp[7 + j];
        float recv = __shfl_xor(send, 16);
        kk[j] = (hi16 ? kp[7 + j] : kp[j]) + recv;
    }

    // ---- pass 3: taps t = 7sg+j; partial[d] += kk[j] * W[t][lig][d] ----
    float partial[16];
#pragma unroll
    for (int d = 0; d < 16; ++d) partial[d] = 0.f;
    const float* wbase = W + (sg * 7) * 256 + lig * 16;
#pragma unroll
    for (int j = 0; j < 7; ++j) {
        if (sg * 7 + j < 27) {          // sg3,j6 is the pad tap
            const float4* wr = reinterpret_cast<const float4*>(wbase + j * 256);
            float4 a0 = wr[0], a1 = wr[1], a2 = wr[2], a3 = wr[3];
            float at_ = kk[j];
            partial[0]  += at_ * a0.x; partial[1]  += at_ * a0.y;
            partial[2]  += at_ * a0.z; partial[3]  += at_ * a0.w;
            partial[4]  += at_ * a1.x; partial[5]  += at_ * a1.y;
            partial[6]  += at_ * a1.z; partial[7]  += at_ * a1.w;
            partial[8]  += at_ * a2.x; partial[9]  += at_ * a2.y;
            partial[10] += at_ * a2.z; partial[11] += at_ * a2.w;
            partial[12] += at_ * a3.x; partial[13] += at_ * a3.y;
            partial[14] += at_ * a3.z; partial[15] += at_ * a3.w;
        }
    }

    // ---- fold-reduce 16 partials across the 16-lane group (R4-proven) ----
#pragma unroll
    for (int half = 8; half >= 1; half >>= 1) {
        bool up = (lig & half) != 0;
#pragma unroll
        for (int j = 0; j < half; ++j) {
            float send = up ? partial[j] : partial[j + half];
            float recv = __shfl_xor(send, half);
            partial[j] = (up ? partial[j + half] : partial[j]) + recv;
        }
    }
    float res = partial[0];
    res += __shfl_xor(res, 16);
    res += __shfl_xor(res, 32);
    res = res / fmaxf((float)nv, 1.f);
    if (lane < 16) out[(size_t)pt * 16 + lig] = res;
#undef LDF
#undef REC_FMA
#undef P2BODY
}

extern "C" void kernel_launch(void* const* d_in, const int* in_sizes, int n_in,
                              void* d_out, int out_size, void* d_ws, size_t ws_size,
                              hipStream_t stream) {
    const float* input = (const float*)d_in[0];   // [2,16,64,64,64]
    const float* pos   = (const float*)d_in[1];   // [2,8192,3]
    const float* W     = (const float*)d_in[2];   // [3,3,3,16,16]
    // d_in[3] grid_pos unused: grid_pos[i] == i*DX exactly
    float* out  = (float*)d_out;
    float* feat = (float*)d_ws;

    const size_t feat_bytes = (size_t)kB * kG * 16 * sizeof(float);
    int use_feat = (d_ws != nullptr && ws_size >= feat_bytes) ? 1 : 0;

    if (use_feat) {
        transpose_feat_k<<<(kB * kG + 255) / 256, 256, 0, stream>>>(input, feat);
        cconv_main<1><<<kPts / PPB, THREADS, 0, stream>>>(input, pos, W, feat, out);
    } else {
        cconv_main<0><<<kPts / PPB, THREADS, 0, stream>>>(input, pos, W, feat, out);
    }
}